// Round 7
// baseline (397.197 us; speedup 1.0000x reference)
//
#include <hip/hip_runtime.h>
#include <hip/hip_bf16.h>

#define N_NODES 65536
#define IN_CH 512
#define HIDDEN 256
#define OUT_CH 8
#define NUM_GRAPHS 32
#define MAX_LEN 4096
#define BN_EPS 1e-5f
#define BN_BLOCKS 2048

using short8  = __attribute__((ext_vector_type(8))) short;
using floatx4 = __attribute__((ext_vector_type(4))) float;
typedef unsigned int u32;
typedef unsigned short u16;

__device__ inline u16 f2b(float f) {
    u32 u = __float_as_uint(f);
    u += 0x7FFFu + ((u >> 16) & 1u);
    return (u16)(u >> 16);
}
// GELU tanh-form via hw exp+rcp; max abs err vs exact-erf ~3e-4.
__device__ inline float gelu_f(float x) {
    float z = x + 0.044715f * x * x * x;
    float e = __builtin_exp2f(-2.3022078f * z);
    return x * __builtin_amdgcn_rcpf(1.0f + e);
}
__device__ inline float tanh_f(float y) {
    y = fminf(fmaxf(y, -20.0f), 20.0f);
    float t = __builtin_exp2f(2.885390082f * y);
    return (t - 1.0f) * __builtin_amdgcn_rcpf(t + 1.0f);
}
__device__ inline void load_lds16(const void* g, void* l) {
    __builtin_amdgcn_global_load_lds(
        (const __attribute__((address_space(1))) u32*)g,
        (__attribute__((address_space(3))) u32*)l, 16, 0, 0);
}

// ---- fused: per-channel sum/sumsq partials + raw bf16 cast of x ----
__global__ __launch_bounds__(256) void statscast_k(const float* __restrict__ x,
                                                   u16* __restrict__ xb,
                                                   float4* __restrict__ partials) {
    __shared__ float4 sS[128];
    __shared__ float4 sQ[128];
    int tid = threadIdx.x;
    int half = tid >> 7;
    int c = tid & 127;
    const float4* x4 = (const float4*)x;
    uint2* xb2 = (uint2*)xb;
    float4 s = make_float4(0.f, 0.f, 0.f, 0.f);
    float4 q = make_float4(0.f, 0.f, 0.f, 0.f);
    int row0 = blockIdx.x * 32;
#pragma unroll
    for (int r = half; r < 32; r += 2) {
        size_t off = (size_t)(row0 + r) * 128 + c;
        float4 v = x4[off];
        s.x += v.x; s.y += v.y; s.z += v.z; s.w += v.w;
        q.x += v.x * v.x; q.y += v.y * v.y; q.z += v.z * v.z; q.w += v.w * v.w;
        uint2 o;
        o.x = (u32)f2b(v.x) | ((u32)f2b(v.y) << 16);
        o.y = (u32)f2b(v.z) | ((u32)f2b(v.w) << 16);
        xb2[off] = o;
    }
    if (half == 1) { sS[c] = s; sQ[c] = q; }
    __syncthreads();
    if (half == 0) {
        float4 s2 = sS[c], q2 = sQ[c];
        s.x += s2.x; s.y += s2.y; s.z += s2.z; s.w += s2.w;
        q.x += q2.x; q.y += q2.y; q.z += q2.z; q.w += q2.w;
        partials[(size_t)blockIdx.x * 256 + c * 2]     = make_float4(s.x, q.x, s.y, q.y);
        partials[(size_t)blockIdx.x * 256 + c * 2 + 1] = make_float4(s.z, q.z, s.w, q.w);
    }
}

// ---- reduce partials -> scale/shift ----
__global__ __launch_bounds__(256) void bn_reduce_k(const float4* __restrict__ partials,
                                                   const float* __restrict__ gamma,
                                                   const float* __restrict__ beta,
                                                   float* __restrict__ scale,
                                                   float* __restrict__ shift) {
    __shared__ float4 sd[256];
    int tid = threadIdx.x;
    int g = blockIdx.x;
    float4 a = make_float4(0.f, 0.f, 0.f, 0.f);
    for (int r = tid; r < BN_BLOCKS; r += 256) {
        float4 v = partials[(size_t)r * 256 + g];
        a.x += v.x; a.y += v.y; a.z += v.z; a.w += v.w;
    }
    sd[tid] = a;
    __syncthreads();
    for (int st = 128; st > 0; st >>= 1) {
        if (tid < st) {
            float4 b = sd[tid + st];
            float4 m = sd[tid];
            m.x += b.x; m.y += b.y; m.z += b.z; m.w += b.w;
            sd[tid] = m;
        }
        __syncthreads();
    }
    if (tid == 0) {
        float4 t = sd[0];
        int c0 = g * 2, c1 = g * 2 + 1;
        const float inv = 1.0f / N_NODES;
        float mu0 = t.x * inv, var0 = t.y * inv - mu0 * mu0;
        float mu1 = t.z * inv, var1 = t.w * inv - mu1 * mu1;
        float sc0 = gamma[c0] * rsqrtf(var0 + BN_EPS);
        float sc1 = gamma[c1] * rsqrtf(var1 + BN_EPS);
        scale[c0] = sc0; shift[c0] = beta[c0] - mu0 * sc0;
        scale[c1] = sc1; shift[c1] = beta[c1] - mu1 * sc1;
    }
}

// ---- prep: W transposes/casts + folded bias b1f + graph offsets ----
__global__ __launch_bounds__(256) void prep_k(const float* __restrict__ W1,
                                              const float* __restrict__ W2,
                                              const float* __restrict__ W3,
                                              const float* __restrict__ b1,
                                              const float* __restrict__ scale,
                                              const float* __restrict__ shift,
                                              u16* __restrict__ W1T,
                                              u16* __restrict__ W2T,
                                              u16* __restrict__ W3T,
                                              float* __restrict__ b1f,
                                              const int* __restrict__ batch,
                                              int* __restrict__ offsets) {
    int bid = blockIdx.x;
    int tid = threadIdx.x;
    if (bid < 1792) {
        int idx = bid * 256 + tid;
        if (idx < 262144) {                       // W1 [512,512]
            int k = idx >> 9, m = idx & 511;
            W1T[(size_t)m * 512 + k] = f2b(scale[k] * W1[idx]);
        } else if (idx < 262144 + 131072) {       // W2 [512,256]
            int i = idx - 262144;
            int k = i >> 8, m = i & 255;
            W2T[(size_t)m * 512 + k] = f2b(W2[i]);
        } else {                                  // W3 [256,256]
            int i = idx - 393216;
            int k = i >> 8, m = i & 255;
            W3T[(size_t)m * 256 + k] = f2b(W3[i]);
        }
        if (bid == 0 && tid < NUM_GRAPHS + 1) {
            int gph = tid;
            int lo = 0, hi = N_NODES;
            while (lo < hi) {
                int mid = (lo + hi) >> 1;
                if (batch[mid] < gph) lo = mid + 1; else hi = mid;
            }
            offsets[gph] = lo;
        }
    } else {
        int m = (bid - 1792) * 256 + tid;
        float acc = b1[m];
#pragma unroll 16
        for (int k = 0; k < 512; ++k) acc += shift[k] * W1[k * 512 + m];
        b1f[m] = acc;
    }
}

// ---------------- GEMM1: h1 = gelu(xb @ W1T^T + b1f) ----------------
// 256x128 block tile, 512 threads, BK=64, XCD remap, swizzle, swapped MFMA.
__global__ __launch_bounds__(512) void gemm1_k(const u16* __restrict__ A,
                                               const u16* __restrict__ BT,
                                               const float* __restrict__ bias,
                                               u16* __restrict__ C) {
    const int K = 512, M = 512;
    __shared__ __align__(16) u16 As[256 * 64];   // 32KB
    __shared__ __align__(16) u16 Bs[128 * 64];   // 16KB
    int tid = threadIdx.x;
    int lane = tid & 63;
    int bid = blockIdx.x;
    int xcd = bid & 7;
    int slot = bid >> 3;
    int rloc = slot >> 2;
    int colb = slot & 3;
    int row0 = (xcd * 32 + rloc) * 256;
    int col0 = colb * 128;
    int wave = tid >> 6;
    int wr = (wave >> 1) * 64;
    int wc = (wave & 1) * 64;
    int l15 = lane & 15;
    int q = lane >> 4;

    floatx4 acc[4][4] = {};

    for (int kt = 0; kt < 8; ++kt) {
        int k0 = kt << 6;
#pragma unroll
        for (int s = 0; s < 4; ++s) {
            int li = s * 512 + tid;
            int r = li >> 3;
            int g = li & 7;
            int gs = g ^ (r & 7);
            load_lds16(&A[(size_t)(row0 + r) * K + k0 + gs * 8], &As[li * 8]);
        }
#pragma unroll
        for (int s = 0; s < 2; ++s) {
            int li = s * 512 + tid;
            int r = li >> 3;
            int g = li & 7;
            int gs = g ^ (r & 7);
            load_lds16(&BT[(size_t)(col0 + r) * K + k0 + gs * 8], &Bs[li * 8]);
        }
        __syncthreads();
#pragma unroll
        for (int ks = 0; ks < 2; ++ks) {
            int gidx = ks * 4 + q;
            short8 af[4], bg[4];
#pragma unroll
            for (int i = 0; i < 4; ++i) {
                int row = wr + i * 16 + l15;
                af[i] = *(const short8*)&As[row * 64 + (gidx ^ (row & 7)) * 8];
            }
#pragma unroll
            for (int j = 0; j < 4; ++j) {
                int row = wc + j * 16 + l15;
                bg[j] = *(const short8*)&Bs[row * 64 + (gidx ^ (row & 7)) * 8];
            }
#pragma unroll
            for (int i = 0; i < 4; ++i)
#pragma unroll
                for (int j = 0; j < 4; ++j)
                    acc[i][j] = __builtin_amdgcn_mfma_f32_16x16x32_bf16(bg[j], af[i], acc[i][j], 0, 0, 0);
        }
        __syncthreads();
    }
#pragma unroll
    for (int i = 0; i < 4; ++i) {
        size_t rbase = (size_t)(row0 + wr + i * 16 + l15) * M;
#pragma unroll
        for (int j = 0; j < 4; ++j) {
            int c = col0 + wc + j * 16 + q * 4;
            float4 b4 = *(const float4*)&bias[c];
            float v0 = gelu_f(acc[i][j][0] + b4.x);
            float v1 = gelu_f(acc[i][j][1] + b4.y);
            float v2 = gelu_f(acc[i][j][2] + b4.z);
            float v3 = gelu_f(acc[i][j][3] + b4.w);
            uint2 pk;
            pk.x = (u32)f2b(v0) | ((u32)f2b(v1) << 16);
            pk.y = (u32)f2b(v2) | ((u32)f2b(v3) << 16);
            *(uint2*)&C[rbase + c] = pk;
        }
    }
}

// ---------------- fused tail: h3 = (gelu(h1 @ W2T^T + b2)) @ W3T^T + b3 ----------------
// 1024 blocks x 256 threads (4 waves), 64 rows/block. Phase 1: A staged via
// global_load_lds (8KB/kt), weights W2T streamed global->VGPR (L2-hot), h2
// written to LDS only (swizzled). Phase 2: pure-LDS A + streamed W3T, ZERO
// barriers. h2 never touches global memory.
__global__ __launch_bounds__(256, 3) void mlp_tail_k(const u16* __restrict__ h1,
                                                     const u16* __restrict__ W2T,
                                                     const u16* __restrict__ W3T,
                                                     const float* __restrict__ b2,
                                                     const float* __restrict__ b3,
                                                     u16* __restrict__ h3) {
    __shared__ __align__(16) u16 As[64 * 64];    // 8KB staging
    __shared__ __align__(16) u16 H2[64 * 256];   // 32KB h2 tile
    int tid = threadIdx.x;
    int lane = tid & 63;
    int w = tid >> 6;            // wave 0..3 -> h2/h3 cols [w*64, w*64+64)
    int l15 = lane & 15;
    int q = lane >> 4;
    int row0 = blockIdx.x * 64;

    // ---- phase 1: h2 tile = gelu(h1_tile @ W2T^T + b2) ----
    {
        floatx4 acc[4][4] = {};
        for (int kt = 0; kt < 8; ++kt) {
            int k0 = kt << 6;
#pragma unroll
            for (int s = 0; s < 2; ++s) {        // 512 chunks of 16B
                int li = s * 256 + tid;
                int r = li >> 3;
                int g = li & 7;
                int gs = g ^ (r & 7);
                load_lds16(&h1[(size_t)(row0 + r) * 512 + k0 + gs * 8], &As[li * 8]);
            }
            __syncthreads();
#pragma unroll
            for (int ks = 0; ks < 2; ++ks) {
                int gidx = ks * 4 + q;
                short8 af[4], bg[4];
#pragma unroll
                for (int j = 0; j < 4; ++j)
                    bg[j] = *(const short8*)&W2T[(size_t)(w * 64 + j * 16 + l15) * 512 + k0 + ks * 32 + q * 8];
#pragma unroll
                for (int i = 0; i < 4; ++i) {
                    int row = i * 16 + l15;
                    af[i] = *(const short8*)&As[row * 64 + (gidx ^ (row & 7)) * 8];
                }
#pragma unroll
                for (int i = 0; i < 4; ++i)
#pragma unroll
                    for (int j = 0; j < 4; ++j)
                        acc[i][j] = __builtin_amdgcn_mfma_f32_16x16x32_bf16(bg[j], af[i], acc[i][j], 0, 0, 0);
            }
            __syncthreads();
        }
        // epilogue -> LDS H2 [row][256], 16B-group swizzled (group ^= row&7)
#pragma unroll
        for (int j = 0; j < 4; ++j) {
            int cl = w * 64 + j * 16 + q * 4;            // 4 consecutive cols
            float4 b4 = *(const float4*)&b2[cl];
            int gg = cl >> 3;                            // 16B group 0..31
            int half = (q & 1) * 4;                      // which 8B half
#pragma unroll
            for (int i = 0; i < 4; ++i) {
                int row = i * 16 + l15;
                int sg = (gg & ~7) | ((gg ^ row) & 7);
                float v0 = gelu_f(acc[i][j][0] + b4.x);
                float v1 = gelu_f(acc[i][j][1] + b4.y);
                float v2 = gelu_f(acc[i][j][2] + b4.z);
                float v3 = gelu_f(acc[i][j][3] + b4.w);
                uint2 pk;
                pk.x = (u32)f2b(v0) | ((u32)f2b(v1) << 16);
                pk.y = (u32)f2b(v2) | ((u32)f2b(v3) << 16);
                *(uint2*)&H2[row * 256 + sg * 8 + half] = pk;
            }
        }
    }
    __syncthreads();

    // ---- phase 2: h3 tile = h2_tile @ W3T^T + b3 (no act), no barriers ----
    {
        floatx4 acc[4][4] = {};
#pragma unroll
        for (int ks = 0; ks < 8; ++ks) {                 // K=256, 8 chunks of 32
            int g2 = ks * 4 + q;                         // group 0..31
            short8 af[4], bg[4];
#pragma unroll
            for (int j = 0; j < 4; ++j)
                bg[j] = *(const short8*)&W3T[(size_t)(w * 64 + j * 16 + l15) * 256 + ks * 32 + q * 8];
#pragma unroll
            for (int i = 0; i < 4; ++i) {
                int row = i * 16 + l15;
                int sg = (g2 & ~7) | ((g2 ^ row) & 7);
                af[i] = *(const short8*)&H2[row * 256 + sg * 8];
            }
#pragma unroll
            for (int i = 0; i < 4; ++i)
#pragma unroll
                for (int j = 0; j < 4; ++j)
                    acc[i][j] = __builtin_amdgcn_mfma_f32_16x16x32_bf16(bg[j], af[i], acc[i][j], 0, 0, 0);
        }
#pragma unroll
        for (int i = 0; i < 4; ++i) {
            size_t rbase = (size_t)(row0 + i * 16 + l15) * 256;
#pragma unroll
            for (int j = 0; j < 4; ++j) {
                int c = w * 64 + j * 16 + q * 4;
                float4 b4 = *(const float4*)&b3[c];
                float v0 = acc[i][j][0] + b4.x;
                float v1 = acc[i][j][1] + b4.y;
                float v2 = acc[i][j][2] + b4.z;
                float v3 = acc[i][j][3] + b4.w;
                uint2 pk;
                pk.x = (u32)f2b(v0) | ((u32)f2b(v1) << 16);
                pk.y = (u32)f2b(v2) | ((u32)f2b(v3) << 16);
                *(uint2*)&h3[rbase + c] = pk;
            }
        }
    }
}

// ---- head (destination-ordered, fill fused) ----
__global__ __launch_bounds__(256) void head_k(const u16* __restrict__ h3,
                                              const float* __restrict__ Wo,
                                              const float* __restrict__ bo,
                                              const int* __restrict__ offsets,
                                              const float* __restrict__ alpha_p,
                                              const float* __restrict__ dyt_w,
                                              const float* __restrict__ dyt_b,
                                              float* __restrict__ out) {
    __shared__ float sWo[HIDDEN * OUT_CH];
    __shared__ int soff[NUM_GRAPHS + 1];
    int tid = threadIdx.x;
#pragma unroll
    for (int i = 0; i < 8; ++i) sWo[i * 256 + tid] = Wo[i * 256 + tid];
    if (tid < NUM_GRAPHS + 1) soff[tid] = offsets[tid];
    __syncthreads();
    int idx = blockIdx.x * 256 + tid;
    int g = idx & 31;
    int p = idx >> 5;
    int n = soff[g] + p;
    bool valid = n < soff[g + 1];
    float acc[8];
#pragma unroll
    for (int c = 0; c < 8; ++c) acc[c] = bo[c];
    if (valid) {
        const uint4* hr = (const uint4*)(h3 + (size_t)n * HIDDEN);
#pragma unroll 4
        for (int kk = 0; kk < 32; ++kk) {
            uint4 v = hr[kk];
            u32 u[4] = {v.x, v.y, v.z, v.w};
#pragma unroll
            for (int pp = 0; pp < 4; ++pp) {
                float h0 = __uint_as_float(u[pp] << 16);
                float h1 = __uint_as_float(u[pp] & 0xFFFF0000u);
                const float* w0 = &sWo[(kk * 8 + pp * 2) * 8];
                const float* w1 = w0 + 8;
#pragma unroll
                for (int c = 0; c < 8; ++c) acc[c] += h0 * w0[c];
#pragma unroll
                for (int c = 0; c < 8; ++c) acc[c] += h1 * w1[c];
            }
        }
    }
    float alpha = alpha_p[0];
    float res[8];
#pragma unroll
    for (int c = 0; c < 8; ++c) {
        float a = gelu_f(acc[c]);
        a = dyt_w[c] * tanh_f(alpha * a) + dyt_b[c];
        res[c] = tanh_f(a);
    }
    float4* o = (float4*)(out + (size_t)idx * OUT_CH);
    o[0] = make_float4(res[0], res[1], res[2], res[3]);
    o[1] = make_float4(res[4], res[5], res[6], res[7]);
}

extern "C" void kernel_launch(void* const* d_in, const int* in_sizes, int n_in,
                              void* d_out, int out_size, void* d_ws, size_t ws_size,
                              hipStream_t stream) {
    (void)in_sizes; (void)n_in; (void)out_size; (void)ws_size;
    const float* x_res = (const float*)d_in[0];
    const int*   batch = (const int*)d_in[1];
    const float* gamma = (const float*)d_in[2];
    const float* beta  = (const float*)d_in[3];
    const float* W1    = (const float*)d_in[4];
    const float* b1    = (const float*)d_in[5];
    const float* W2    = (const float*)d_in[6];
    const float* b2    = (const float*)d_in[7];
    const float* W3    = (const float*)d_in[8];
    const float* b3    = (const float*)d_in[9];
    const float* Wo    = (const float*)d_in[10];
    const float* bo    = (const float*)d_in[11];
    const float* alpha = (const float*)d_in[12];
    const float* dyt_w = (const float*)d_in[13];
    const float* dyt_b = (const float*)d_in[14];
    float* out = (float*)d_out;

    char* ws = (char*)d_ws;
    float* scale = (float*)(ws + 0);
    float* shift = (float*)(ws + 2048);
    float* b1f   = (float*)(ws + 4096);
    int*   offs  = (int*)(ws + 8192);
    u16* W1T = (u16*)(ws + 16384);                       // 512KB
    u16* W2T = (u16*)(ws + 16384 + 524288);              // 256KB
    u16* W3T = (u16*)(ws + 16384 + 524288 + 262144);     // 128KB
    const size_t MB = 1024 * 1024;
    u16* xb = (u16*)(ws + 2 * MB);              // 64MB  [2,66)   dead after gemm1
    u16* h1 = (u16*)(ws + 66 * MB);             // 64MB  [66,130) tail input
    u16* h3 = (u16*)(ws + 2 * MB);              // 32MB  (aliases xb)
    float4* partials = (float4*)(ws + 66 * MB); // 8MB   (aliases h1; dead before gemm1)

    statscast_k<<<BN_BLOCKS, 256, 0, stream>>>(x_res, xb, partials);
    bn_reduce_k<<<256, 256, 0, stream>>>(partials, gamma, beta, scale, shift);
    prep_k<<<1794, 256, 0, stream>>>(W1, W2, W3, b1, scale, shift,
                                     W1T, W2T, W3T, b1f, batch, offs);
    gemm1_k<<<1024, 512, 0, stream>>>(xb, W1T, b1f, h1);
    mlp_tail_k<<<1024, 256, 0, stream>>>(h1, W2T, W3T, b2, b3, h3);
    head_k<<<512, 256, 0, stream>>>(h3, Wo, bo, offs, alpha, dyt_w, dyt_b, out);
}